// Round 3
// baseline (1744.510 us; speedup 1.0000x reference)
//
#include <hip/hip_runtime.h>
#include <math.h>

typedef float v2f __attribute__((ext_vector_type(2)));

#define LN2_INV 1.4426950408889634f

__device__ __forceinline__ float fexp2(float x) {
#if __has_builtin(__builtin_amdgcn_exp2f)
    return __builtin_amdgcn_exp2f(x);
#else
    return exp2f(x);
#endif
}

__device__ __forceinline__ v2f max2(v2f a, float b) {
    v2f r; r.x = fmaxf(a.x, b); r.y = fmaxf(a.y, b); return r;
}
__device__ __forceinline__ v2f min2(v2f a, float b) {
    v2f r; r.x = fminf(a.x, b); r.y = fminf(a.y, b); return r;
}

// v += dpp_shifted(v) within 16-lane rows; shifted-in lanes contribute 0.
#define DPP_ROW_ADD(V, CTRL) \
    V += __int_as_float(__builtin_amdgcn_update_dpp(0, __float_as_int(V), CTRL, 0xf, 0xf, true));

// ---------------------------------------------------------------------------
// k_h0: h0 = relu(x @ f_W + f_b), x [N,128], f_W [128,64]. 8 nodes/block.
// ---------------------------------------------------------------------------
__global__ __launch_bounds__(256) void k_h0(const float* __restrict__ x,
                                            const float* __restrict__ fW,
                                            const float* __restrict__ fb,
                                            float* __restrict__ h0) {
    __shared__ __align__(16) float xs[8 * 128];
    int t = threadIdx.x;
    int base = blockIdx.x * 8;
#pragma unroll
    for (int r = 0; r < 4; ++r) { int j = r * 256 + t; xs[j] = x[base * 128 + j]; }
    __syncthreads();
    int c = t & 63, half = t >> 6;
    float acc0 = fb[c], acc1 = fb[c];
    int m0 = half, m1 = half + 4;
#pragma unroll 8
    for (int k0 = 0; k0 < 128; k0 += 4) {
        float4 a = *(const float4*)&xs[m0 * 128 + k0];
        float4 b = *(const float4*)&xs[m1 * 128 + k0];
        float w0 = fW[(k0 + 0) * 64 + c], w1 = fW[(k0 + 1) * 64 + c];
        float w2 = fW[(k0 + 2) * 64 + c], w3 = fW[(k0 + 3) * 64 + c];
        acc0 = fmaf(a.x, w0, fmaf(a.y, w1, fmaf(a.z, w2, fmaf(a.w, w3, acc0))));
        acc1 = fmaf(b.x, w0, fmaf(b.y, w1, fmaf(b.z, w2, fmaf(b.w, w3, acc1))));
    }
    h0[(base + m0) * 64 + c] = fmaxf(acc0, 0.f);
    h0[(base + m1) * 64 + c] = fmaxf(acc1, 0.f);
}

// ---------------------------------------------------------------------------
// k_xlxr: xl = h@Wl + bl, xr = h@Wr + br, natural [N][256] layout (h*64+d).
// 16 nodes per block, thread t = output column.
// ---------------------------------------------------------------------------
__global__ __launch_bounds__(256) void k_xlxr(const float* __restrict__ h,
                                              const float* __restrict__ Wl,
                                              const float* __restrict__ Wr,
                                              const float* __restrict__ bl,
                                              const float* __restrict__ br,
                                              float* __restrict__ xl,
                                              float* __restrict__ xr) {
    __shared__ __align__(16) float hs[16 * 64];
    int t = threadIdx.x;
    int base = blockIdx.x * 16;
#pragma unroll
    for (int r = 0; r < 4; ++r) hs[r * 256 + t] = h[base * 64 + r * 256 + t];
    __syncthreads();
    float bL = bl[t], bR = br[t];
    float accl[16], accr[16];
#pragma unroll
    for (int m = 0; m < 16; ++m) { accl[m] = bL; accr[m] = bR; }
#pragma unroll 4
    for (int k0 = 0; k0 < 64; k0 += 4) {
        float wl[4], wr[4];
#pragma unroll
        for (int q = 0; q < 4; ++q) {
            wl[q] = Wl[(k0 + q) * 256 + t];
            wr[q] = Wr[(k0 + q) * 256 + t];
        }
#pragma unroll
        for (int m = 0; m < 16; ++m) {
            float4 hv = *(const float4*)&hs[m * 64 + k0];
            accl[m] = fmaf(hv.x, wl[0], fmaf(hv.y, wl[1], fmaf(hv.z, wl[2], fmaf(hv.w, wl[3], accl[m]))));
            accr[m] = fmaf(hv.x, wr[0], fmaf(hv.y, wr[1], fmaf(hv.z, wr[2], fmaf(hv.w, wr[3], accr[m]))));
        }
    }
#pragma unroll
    for (int m = 0; m < 16; ++m) {
        xl[(base + m) * 256 + t] = accl[m];
        xr[(base + m) * 256 + t] = accr[m];
    }
}

// ---------------------------------------------------------------------------
// CSR build. rec record (stride 24 ints): [0..19] = relu edge-MLP s_k,
// [20] = src node, [21..23] pad. Written at the CSR position directly.
// ---------------------------------------------------------------------------
__global__ void k_zero(int* __restrict__ deg, int* __restrict__ counter, int Nn) {
    int i = blockIdx.x * 256 + threadIdx.x;
    if (i < Nn) deg[i] = 0;
    if (i == 0) *counter = 0;
}

__global__ void k_count(const int* __restrict__ dstArr, int* __restrict__ deg, int Ee) {
    int e = blockIdx.x * 256 + threadIdx.x;
    if (e < Ee) atomicAdd(&deg[dstArr[e]], 1);
}

__global__ void k_alloc(const int* __restrict__ deg, int* __restrict__ counter,
                        int* __restrict__ start, int* __restrict__ cursor, int Nn) {
    int n = blockIdx.x * 256 + threadIdx.x;
    if (n < Nn) {
        int d = deg[n];
        int b = atomicAdd(counter, d);
        start[n] = b;
        cursor[n] = b;
    }
}

__global__ void k_fill(const int* __restrict__ dstArr, const int* __restrict__ srcArr,
                       const float* __restrict__ eattr, const float* __restrict__ feW,
                       const float* __restrict__ feb, int* __restrict__ cursor,
                       int* __restrict__ rec, int Ee) {
    int e = blockIdx.x * 256 + threadIdx.x;
    if (e >= Ee) return;
    float a0 = eattr[2 * e], a1 = eattr[2 * e + 1];
    int p = atomicAdd(&cursor[dstArr[e]], 1);
    float* r = (float*)(rec + (size_t)p * 24);
    float s[20];
#pragma unroll
    for (int k = 0; k < 20; ++k)
        s[k] = fmaxf(fmaf(a0, feW[k], fmaf(a1, feW[20 + k], feb[k])), 0.f);
#pragma unroll
    for (int j = 0; j < 5; ++j)
        ((float4*)r)[j] = make_float4(s[4 * j], s[4 * j + 1], s[4 * j + 2], s[4 * j + 3]);
    ((int*)r)[20] = srcArr[e];
}

// ---------------------------------------------------------------------------
// k_edge: one wave per dst node. Lane = h*16+g; lane holds dims 4g..4g+3 of
// head h (== natural h*64+d order). Per-edge: scalar-pipe record (s_k, src),
// 40-80 FMA edge-embed, pk leaky-relu/att, 16-lane DPP reduce + bpermute
// broadcast, 1 exp2, pk accumulate. Records 2-ahead, xl gather 1-ahead.
// ---------------------------------------------------------------------------
__global__ __launch_bounds__(256, 3) void k_edge(
    const float4* __restrict__ xl4p, const float4* __restrict__ xr4p,
    const float* __restrict__ att, const float4* __restrict__ We4,
    const int* __restrict__ rec, const int* __restrict__ start,
    const int* __restrict__ deg, const float* __restrict__ bias,
    float* __restrict__ hout, int Nn) {
    const int lane = threadIdx.x & 63;
    const int n = (int)((blockIdx.x * 256u + threadIdx.x) >> 6);
    if (n >= Nn) return;

    const int dn = __builtin_amdgcn_readfirstlane(deg[n]);
    float4 bias4 = ((const float4*)bias)[lane & 15];
    if (dn == 0) {
        if (lane < 16) {
            float4 o = make_float4(fmaxf(bias4.x, 0.f), fmaxf(bias4.y, 0.f),
                                   fmaxf(bias4.z, 0.f), fmaxf(bias4.w, 0.f));
            ((float4*)hout)[(size_t)n * 16 + lane] = o;
        }
        return;
    }
    const int s0 = __builtin_amdgcn_readfirstlane(start[n]);
    const int* rb = rec + (size_t)s0 * 24;

    // wave-invariant operands
    float4 attv = ((const float4*)att)[lane];
    v2f att01 = {attv.x * LN2_INV, attv.y * LN2_INV};
    v2f att23 = {attv.z * LN2_INV, attv.w * LN2_INV};
    v2f at201 = 0.2f * att01, at223 = 0.2f * att23;
    float4 xrv = xr4p[(size_t)n * 64 + lane];
    v2f xr01 = {xrv.x, xrv.y}, xr23 = {xrv.z, xrv.w};
    v2f we01[20], we23[20];
#pragma unroll
    for (int k = 0; k < 20; ++k) {
        float4 w = We4[k * 64 + lane];
        we01[k].x = w.x; we01[k].y = w.y;
        we23[k].x = w.z; we23[k].y = w.w;
    }
    const int bperm = ((lane & 48) | 15) << 2;

    v2f acc01 = {0.f, 0.f}, acc23 = {0.f, 0.f};
    float l = 0.f;

    float sA[20], sB[20];
    int src1, src2;

#define LOADS(BUF, IDX)                                                     \
    {                                                                       \
        const int* q_ = rb + (size_t)(IDX) * 24;                            \
        _Pragma("unroll")                                                   \
        for (int k_ = 0; k_ < 20; ++k_) BUF[k_] = __int_as_float(q_[k_]);   \
    }

#define PROC(SBUF, XL)                                                      \
    {                                                                       \
        v2f xl01 = {XL.x, XL.y}, xl23 = {XL.z, XL.w};                       \
        v2f ee01 = SBUF[0] * we01[0];                                       \
        v2f ee23 = SBUF[0] * we23[0];                                       \
        _Pragma("unroll")                                                   \
        for (int k_ = 1; k_ < 20; ++k_) {                                   \
            ee01 += SBUF[k_] * we01[k_];                                    \
            ee23 += SBUF[k_] * we23[k_];                                    \
        }                                                                   \
        v2f v01 = xl01 + xr01 + ee01;                                       \
        v2f v23 = xl23 + xr23 + ee23;                                       \
        v2f p01 = att01 * max2(v01, 0.f) + at201 * min2(v01, 0.f);          \
        v2f p23 = att23 * max2(v23, 0.f) + at223 * min2(v23, 0.f);          \
        v2f pr = p01 + p23;                                                 \
        float ps = pr.x + pr.y;                                             \
        DPP_ROW_ADD(ps, 0x111)                                              \
        DPP_ROW_ADD(ps, 0x112)                                              \
        DPP_ROW_ADD(ps, 0x114)                                              \
        DPP_ROW_ADD(ps, 0x118)                                              \
        float sc = __int_as_float(                                          \
            __builtin_amdgcn_ds_bpermute(bperm, __float_as_int(ps)));       \
        float w_ = fexp2(sc);                                               \
        l += w_;                                                            \
        acc01 += w_ * xl01;                                                 \
        acc23 += w_ * xl23;                                                 \
    }

    // prologue: records for edges 0,1; srcs for 0,1; gather edge 0
    int i1 = dn > 1 ? 1 : 0;
    LOADS(sA, 0)
    int srcA0 = rb[20];
    src1 = rb[(size_t)i1 * 24 + 20];
    LOADS(sB, i1)
    float4 xlA = xl4p[(size_t)srcA0 * 64 + lane];
    float4 xlB;

    int i = 0;
    while (true) {
        // ---- even edge i: consume sA, xlA ----
        {
            int ip2 = i + 2 < dn ? i + 2 : dn - 1;
            src2 = rb[(size_t)ip2 * 24 + 20];
            xlB = xl4p[(size_t)src1 * 64 + lane];    // edge i+1
            PROC(sA, xlA)
            LOADS(sA, ip2)                           // edge i+2 -> sA
            src1 = src2;
        }
        if (++i >= dn) break;
        // ---- odd edge i: consume sB, xlB ----
        {
            int ip2 = i + 2 < dn ? i + 2 : dn - 1;
            src2 = rb[(size_t)ip2 * 24 + 20];
            xlA = xl4p[(size_t)src1 * 64 + lane];    // edge i+1
            PROC(sB, xlB)
            LOADS(sB, ip2)                           // edge i+2 -> sB
            src1 = src2;
        }
        if (++i >= dn) break;
    }

    // epilogue: res = relu(bias + 0.25 * sum_h acc_h / l_h)
    float inv = 0.25f / l;
    float4 r = make_float4(acc01.x * inv, acc01.y * inv, acc23.x * inv, acc23.y * inv);
    r.x += __shfl_xor(r.x, 16, 64); r.x += __shfl_xor(r.x, 32, 64);
    r.y += __shfl_xor(r.y, 16, 64); r.y += __shfl_xor(r.y, 32, 64);
    r.z += __shfl_xor(r.z, 16, 64); r.z += __shfl_xor(r.z, 32, 64);
    r.w += __shfl_xor(r.w, 16, 64); r.w += __shfl_xor(r.w, 32, 64);
    if (lane < 16) {
        float4 o = make_float4(fmaxf(r.x + bias4.x, 0.f), fmaxf(r.y + bias4.y, 0.f),
                               fmaxf(r.z + bias4.z, 0.f), fmaxf(r.w + bias4.w, 0.f));
        ((float4*)hout)[(size_t)n * 16 + lane] = o;
    }
#undef LOADS
#undef PROC
}

// ---------------------------------------------------------------------------
extern "C" void kernel_launch(void* const* d_in, const int* in_sizes, int n_in,
                              void* d_out, int out_size, void* d_ws, size_t ws_size,
                              hipStream_t stream) {
    const float* x     = (const float*)d_in[0];
    const float* eattr = (const float*)d_in[1];
    const int*   eidx  = (const int*)d_in[2];
    const float* fW    = (const float*)d_in[3];
    const float* fb    = (const float*)d_in[4];
    const float* feW   = (const float*)d_in[5];
    const float* feb   = (const float*)d_in[6];
    const float* Wl    = (const float*)d_in[7];
    const float* bl    = (const float*)d_in[8];
    const float* Wr    = (const float*)d_in[9];
    const float* br    = (const float*)d_in[10];
    const float* We    = (const float*)d_in[11];
    const float* att   = (const float*)d_in[12];
    const float* bias  = (const float*)d_in[13];
    float* out = (float*)d_out;

    const int N = in_sizes[0] / 128;   // 50000
    const int E = in_sizes[1] / 2;     // 800000
    const int* srcArr = eidx;
    const int* dstArr = eidx + E;

    char* p = (char*)d_ws;
    auto alloc = [&](size_t bytes) -> char* {
        char* r = p;
        p += (bytes + 255) & ~(size_t)255;
        return r;
    };
    float* hA   = (float*)alloc((size_t)N * 64 * 4);
    float* hB   = (float*)alloc((size_t)N * 64 * 4);
    float* xl   = (float*)alloc((size_t)N * 256 * 4);
    float* xr   = (float*)alloc((size_t)N * 256 * 4);
    int* deg    = (int*)alloc((size_t)N * 4);
    int* start  = (int*)alloc((size_t)N * 4);
    int* cursor = (int*)alloc((size_t)N * 4);
    int* counter = (int*)alloc(256);
    int* rec    = (int*)alloc((size_t)E * 24 * 4);

    k_h0<<<N / 8, 256, 0, stream>>>(x, fW, fb, hA);
    k_zero<<<(N + 255) / 256, 256, 0, stream>>>(deg, counter, N);
    k_count<<<(E + 255) / 256, 256, 0, stream>>>(dstArr, deg, E);
    k_alloc<<<(N + 255) / 256, 256, 0, stream>>>(deg, counter, start, cursor, N);
    k_fill<<<(E + 255) / 256, 256, 0, stream>>>(dstArr, srcArr, eattr, feW, feb,
                                                cursor, rec, E);

    const float* hin = hA;
    for (int layer = 0; layer < 3; ++layer) {
        float* hout = (layer == 2) ? out : ((layer == 0) ? hB : hA);
        k_xlxr<<<N / 16, 256, 0, stream>>>(hin, Wl, Wr, bl, br, xl, xr);
        k_edge<<<(N * 64) / 256, 256, 0, stream>>>(
            (const float4*)xl, (const float4*)xr, att, (const float4*)We,
            rec, start, deg, bias, hout, N);
        hin = hout;
    }
}

// Round 4
// 919.195 us; speedup vs baseline: 1.8979x; 1.8979x over previous
//
#include <hip/hip_runtime.h>
#include <math.h>

typedef float v2f __attribute__((ext_vector_type(2)));

#define LN2_INV 1.4426950408889634f

__device__ __forceinline__ float fexp2(float x) {
#if __has_builtin(__builtin_amdgcn_exp2f)
    return __builtin_amdgcn_exp2f(x);
#else
    return exp2f(x);
#endif
}

__device__ __forceinline__ int rdlane_i(int v, int k) {
    return __builtin_amdgcn_readlane(v, k);
}

__device__ __forceinline__ v2f max2(v2f a, float b) {
    v2f r; r.x = fmaxf(a.x, b); r.y = fmaxf(a.y, b); return r;
}
__device__ __forceinline__ v2f min2(v2f a, float b) {
    v2f r; r.x = fminf(a.x, b); r.y = fminf(a.y, b); return r;
}

// v += dpp_shifted(v) within 16-lane rows; shifted-in lanes contribute 0.
#define DPP_ROW_ADD(V, CTRL) \
    V += __int_as_float(__builtin_amdgcn_update_dpp(0, __float_as_int(V), CTRL, 0xf, 0xf, true));

// ---------------------------------------------------------------------------
// k_h0: h0 = relu(x @ f_W + f_b), x [N,128], f_W [128,64]. 8 nodes/block.
// ---------------------------------------------------------------------------
__global__ __launch_bounds__(256) void k_h0(const float* __restrict__ x,
                                            const float* __restrict__ fW,
                                            const float* __restrict__ fb,
                                            float* __restrict__ h0) {
    __shared__ __align__(16) float xs[8 * 128];
    int t = threadIdx.x;
    int base = blockIdx.x * 8;
#pragma unroll
    for (int r = 0; r < 4; ++r) { int j = r * 256 + t; xs[j] = x[base * 128 + j]; }
    __syncthreads();
    int c = t & 63, half = t >> 6;
    float acc0 = fb[c], acc1 = fb[c];
    int m0 = half, m1 = half + 4;
#pragma unroll 8
    for (int k0 = 0; k0 < 128; k0 += 4) {
        float4 a = *(const float4*)&xs[m0 * 128 + k0];
        float4 b = *(const float4*)&xs[m1 * 128 + k0];
        float w0 = fW[(k0 + 0) * 64 + c], w1 = fW[(k0 + 1) * 64 + c];
        float w2 = fW[(k0 + 2) * 64 + c], w3 = fW[(k0 + 3) * 64 + c];
        acc0 = fmaf(a.x, w0, fmaf(a.y, w1, fmaf(a.z, w2, fmaf(a.w, w3, acc0))));
        acc1 = fmaf(b.x, w0, fmaf(b.y, w1, fmaf(b.z, w2, fmaf(b.w, w3, acc1))));
    }
    h0[(base + m0) * 64 + c] = fmaxf(acc0, 0.f);
    h0[(base + m1) * 64 + c] = fmaxf(acc1, 0.f);
}

// ---------------------------------------------------------------------------
// k_xlxr: xl = h@Wl + bl, xr = h@Wr + br, natural [N][256] layout (h*64+d).
// 16 nodes per block, thread t = output column.
// ---------------------------------------------------------------------------
__global__ __launch_bounds__(256) void k_xlxr(const float* __restrict__ h,
                                              const float* __restrict__ Wl,
                                              const float* __restrict__ Wr,
                                              const float* __restrict__ bl,
                                              const float* __restrict__ br,
                                              float* __restrict__ xl,
                                              float* __restrict__ xr) {
    __shared__ __align__(16) float hs[16 * 64];
    int t = threadIdx.x;
    int base = blockIdx.x * 16;
#pragma unroll
    for (int r = 0; r < 4; ++r) hs[r * 256 + t] = h[base * 64 + r * 256 + t];
    __syncthreads();
    float bL = bl[t], bR = br[t];
    float accl[16], accr[16];
#pragma unroll
    for (int m = 0; m < 16; ++m) { accl[m] = bL; accr[m] = bR; }
#pragma unroll 4
    for (int k0 = 0; k0 < 64; k0 += 4) {
        float wl[4], wr[4];
#pragma unroll
        for (int q = 0; q < 4; ++q) {
            wl[q] = Wl[(k0 + q) * 256 + t];
            wr[q] = Wr[(k0 + q) * 256 + t];
        }
#pragma unroll
        for (int m = 0; m < 16; ++m) {
            float4 hv = *(const float4*)&hs[m * 64 + k0];
            accl[m] = fmaf(hv.x, wl[0], fmaf(hv.y, wl[1], fmaf(hv.z, wl[2], fmaf(hv.w, wl[3], accl[m]))));
            accr[m] = fmaf(hv.x, wr[0], fmaf(hv.y, wr[1], fmaf(hv.z, wr[2], fmaf(hv.w, wr[3], accr[m]))));
        }
    }
#pragma unroll
    for (int m = 0; m < 16; ++m) {
        xl[(base + m) * 256 + t] = accl[m];
        xr[(base + m) * 256 + t] = accr[m];
    }
}

// ---------------------------------------------------------------------------
// CSR build. rec record (stride 24 ints): [0..19] = relu edge-MLP s_k,
// [20] = src node, [21..23] pad. Written at the CSR position directly.
// ---------------------------------------------------------------------------
__global__ void k_zero(int* __restrict__ deg, int* __restrict__ counter, int Nn) {
    int i = blockIdx.x * 256 + threadIdx.x;
    if (i < Nn) deg[i] = 0;
    if (i == 0) *counter = 0;
}

__global__ void k_count(const int* __restrict__ dstArr, int* __restrict__ deg, int Ee) {
    int e = blockIdx.x * 256 + threadIdx.x;
    if (e < Ee) atomicAdd(&deg[dstArr[e]], 1);
}

__global__ void k_alloc(const int* __restrict__ deg, int* __restrict__ counter,
                        int* __restrict__ start, int* __restrict__ cursor, int Nn) {
    int n = blockIdx.x * 256 + threadIdx.x;
    if (n < Nn) {
        int d = deg[n];
        int b = atomicAdd(counter, d);
        start[n] = b;
        cursor[n] = b;
    }
}

__global__ void k_fill(const int* __restrict__ dstArr, const int* __restrict__ srcArr,
                       const float* __restrict__ eattr, const float* __restrict__ feW,
                       const float* __restrict__ feb, int* __restrict__ cursor,
                       int* __restrict__ rec, int Ee) {
    int e = blockIdx.x * 256 + threadIdx.x;
    if (e >= Ee) return;
    float a0 = eattr[2 * e], a1 = eattr[2 * e + 1];
    int p = atomicAdd(&cursor[dstArr[e]], 1);
    float* r = (float*)(rec + (size_t)p * 24);
    float s[20];
#pragma unroll
    for (int k = 0; k < 20; ++k)
        s[k] = fmaxf(fmaf(a0, feW[k], fmaf(a1, feW[20 + k], feb[k])), 0.f);
#pragma unroll
    for (int j = 0; j < 5; ++j)
        ((float4*)r)[j] = make_float4(s[4 * j], s[4 * j + 1], s[4 * j + 2], s[4 * j + 3]);
    ((int*)r)[20] = srcArr[e];
}

// ---------------------------------------------------------------------------
// k_edge: one wave per dst node. Lane = h*16+g; lane holds dims 4g..4g+3 of
// head h (natural h*64+d order as float4). Edge record read as 1 dword/lane,
// broadcast via readlane directly into packed FMAs (no register arrays).
// Records prefetched 2 ahead, xl gather 1 ahead. 1 exp2/edge.
// ---------------------------------------------------------------------------
__global__ __launch_bounds__(256, 3) void k_edge(
    const float4* __restrict__ xl4p, const float4* __restrict__ xr4p,
    const float* __restrict__ att, const float4* __restrict__ We4,
    const int* __restrict__ rec, const int* __restrict__ start,
    const int* __restrict__ deg, const float* __restrict__ bias,
    float* __restrict__ hout, int Nn) {
    const int lane = threadIdx.x & 63;
    const int n = (int)((blockIdx.x * 256u + threadIdx.x) >> 6);
    if (n >= Nn) return;

    const int dn = __builtin_amdgcn_readfirstlane(deg[n]);
    float4 bias4 = ((const float4*)bias)[lane & 15];
    if (dn == 0) {
        if (lane < 16) {
            float4 o = make_float4(fmaxf(bias4.x, 0.f), fmaxf(bias4.y, 0.f),
                                   fmaxf(bias4.z, 0.f), fmaxf(bias4.w, 0.f));
            ((float4*)hout)[(size_t)n * 16 + lane] = o;
        }
        return;
    }
    const int s0 = __builtin_amdgcn_readfirstlane(start[n]);
    const int* rb = rec + (size_t)s0 * 24 + (lane & 31);

    // wave-invariant operands
    float4 attv = ((const float4*)att)[lane];
    v2f att01 = {attv.x * LN2_INV, attv.y * LN2_INV};
    v2f att23 = {attv.z * LN2_INV, attv.w * LN2_INV};
    v2f at201 = 0.2f * att01, at223 = 0.2f * att23;
    float4 xrv = xr4p[(size_t)n * 64 + lane];
    v2f xr01 = {xrv.x, xrv.y}, xr23 = {xrv.z, xrv.w};
    v2f we01[20], we23[20];
#pragma unroll
    for (int k = 0; k < 20; ++k) {
        float4 w = We4[k * 64 + lane];
        we01[k].x = w.x; we01[k].y = w.y;
        we23[k].x = w.z; we23[k].y = w.w;
    }
    const int bperm = ((lane & 48) | 15) << 2;

    v2f acc01 = {0.f, 0.f}, acc23 = {0.f, 0.f};
    float l = 0.f;

    // prologue: records for edges 0,1; xl gather for edge 0
    int i1 = dn > 1 ? 1 : 0;
    int rv0 = rb[0];
    int rv1 = rb[(size_t)i1 * 24];
    int src0 = rdlane_i(rv0, 20);
    float4 xl0 = xl4p[(size_t)src0 * 64 + lane];

    for (int i = 0; i < dn; ++i) {
        // prefetch: record i+2, xl gather i+1
        int i2 = (i + 2 < dn) ? (i + 2) : (dn - 1);
        int rv2 = rb[(size_t)i2 * 24];
        int src1 = rdlane_i(rv1, 20);
        float4 xl1 = xl4p[(size_t)src1 * 64 + lane];

        v2f xl01 = {xl0.x, xl0.y}, xl23 = {xl0.z, xl0.w};

        // ee[lane] = sum_k s_k * We[k][lane], s_k broadcast via readlane
        v2f ee01, ee23;
        {
            float sk = __int_as_float(rdlane_i(rv0, 0));
            ee01 = sk * we01[0];
            ee23 = sk * we23[0];
        }
#pragma unroll
        for (int k = 1; k < 20; ++k) {
            float sk = __int_as_float(rdlane_i(rv0, k));
            ee01 += sk * we01[k];
            ee23 += sk * we23[k];
        }

        v2f v01 = (xl01 + xr01) + ee01;
        v2f v23 = (xl23 + xr23) + ee23;
        v2f p01 = att01 * max2(v01, 0.f) + at201 * min2(v01, 0.f);
        v2f p23 = att23 * max2(v23, 0.f) + at223 * min2(v23, 0.f);
        v2f pr = p01 + p23;
        float ps = pr.x + pr.y;
        DPP_ROW_ADD(ps, 0x111)
        DPP_ROW_ADD(ps, 0x112)
        DPP_ROW_ADD(ps, 0x114)
        DPP_ROW_ADD(ps, 0x118)
        float sc = __int_as_float(
            __builtin_amdgcn_ds_bpermute(bperm, __float_as_int(ps)));
        float w_ = fexp2(sc);
        l += w_;
        acc01 += w_ * xl01;
        acc23 += w_ * xl23;

        rv0 = rv1; rv1 = rv2; xl0 = xl1;
    }

    // epilogue: res = relu(bias + 0.25 * sum_h acc_h / l_h)
    float inv = 0.25f / l;
    float4 r = make_float4(acc01.x * inv, acc01.y * inv, acc23.x * inv, acc23.y * inv);
    r.x += __shfl_xor(r.x, 16, 64); r.x += __shfl_xor(r.x, 32, 64);
    r.y += __shfl_xor(r.y, 16, 64); r.y += __shfl_xor(r.y, 32, 64);
    r.z += __shfl_xor(r.z, 16, 64); r.z += __shfl_xor(r.z, 32, 64);
    r.w += __shfl_xor(r.w, 16, 64); r.w += __shfl_xor(r.w, 32, 64);
    if (lane < 16) {
        float4 o = make_float4(fmaxf(r.x + bias4.x, 0.f), fmaxf(r.y + bias4.y, 0.f),
                               fmaxf(r.z + bias4.z, 0.f), fmaxf(r.w + bias4.w, 0.f));
        ((float4*)hout)[(size_t)n * 16 + lane] = o;
    }
}

// ---------------------------------------------------------------------------
extern "C" void kernel_launch(void* const* d_in, const int* in_sizes, int n_in,
                              void* d_out, int out_size, void* d_ws, size_t ws_size,
                              hipStream_t stream) {
    const float* x     = (const float*)d_in[0];
    const float* eattr = (const float*)d_in[1];
    const int*   eidx  = (const int*)d_in[2];
    const float* fW    = (const float*)d_in[3];
    const float* fb    = (const float*)d_in[4];
    const float* feW   = (const float*)d_in[5];
    const float* feb   = (const float*)d_in[6];
    const float* Wl    = (const float*)d_in[7];
    const float* bl    = (const float*)d_in[8];
    const float* Wr    = (const float*)d_in[9];
    const float* br    = (const float*)d_in[10];
    const float* We    = (const float*)d_in[11];
    const float* att   = (const float*)d_in[12];
    const float* bias  = (const float*)d_in[13];
    float* out = (float*)d_out;

    const int N = in_sizes[0] / 128;   // 50000
    const int E = in_sizes[1] / 2;     // 800000
    const int* srcArr = eidx;
    const int* dstArr = eidx + E;

    char* p = (char*)d_ws;
    auto alloc = [&](size_t bytes) -> char* {
        char* r = p;
        p += (bytes + 255) & ~(size_t)255;
        return r;
    };
    float* hA   = (float*)alloc((size_t)N * 64 * 4);
    float* hB   = (float*)alloc((size_t)N * 64 * 4);
    float* xl   = (float*)alloc((size_t)N * 256 * 4);
    float* xr   = (float*)alloc((size_t)N * 256 * 4);
    int* deg    = (int*)alloc((size_t)N * 4);
    int* start  = (int*)alloc((size_t)N * 4);
    int* cursor = (int*)alloc((size_t)N * 4);
    int* counter = (int*)alloc(256);
    int* rec    = (int*)alloc((size_t)E * 24 * 4);

    k_h0<<<N / 8, 256, 0, stream>>>(x, fW, fb, hA);
    k_zero<<<(N + 255) / 256, 256, 0, stream>>>(deg, counter, N);
    k_count<<<(E + 255) / 256, 256, 0, stream>>>(dstArr, deg, E);
    k_alloc<<<(N + 255) / 256, 256, 0, stream>>>(deg, counter, start, cursor, N);
    k_fill<<<(E + 255) / 256, 256, 0, stream>>>(dstArr, srcArr, eattr, feW, feb,
                                                cursor, rec, E);

    const float* hin = hA;
    for (int layer = 0; layer < 3; ++layer) {
        float* hout = (layer == 2) ? out : ((layer == 0) ? hB : hA);
        k_xlxr<<<N / 16, 256, 0, stream>>>(hin, Wl, Wr, bl, br, xl, xr);
        k_edge<<<(N * 64) / 256, 256, 0, stream>>>(
            (const float4*)xl, (const float4*)xr, att, (const float4*)We,
            rec, start, deg, bias, hout, N);
        hin = hout;
    }
}